// Round 10
// baseline (391.982 us; speedup 1.0000x reference)
//
#include <hip/hip_runtime.h>
#include <stdint.h>

constexpr int CB   = 4;
constexpr int CS   = 512;
constexpr int CHID = 2048;
constexpr int CNH  = 4;
constexpr int CNM  = 8;
constexpr int CVD  = 2048;   // value dim
constexpr int CHVD = 512;    // per-head value dim
constexpr int CT   = CB * CS;   // 2048 tokens
constexpr int CN4  = 6144;      // q(1024)+k(1024)+v(2048)+g(2048)

typedef __bf16 bf16x8 __attribute__((ext_vector_type(8)));
typedef float  f32x4  __attribute__((ext_vector_type(4)));
typedef unsigned short us4 __attribute__((ext_vector_type(4)));
typedef unsigned short us8 __attribute__((ext_vector_type(8)));

union bfu { us8 u; bf16x8 b; };

__device__ __forceinline__ unsigned short f2bf(float f) {
    union { float f; unsigned int i; } v; v.f = f;
    return (unsigned short)((v.i + 0x7fffu + ((v.i >> 16) & 1u)) >> 16);
}
__device__ __forceinline__ float bf2f(unsigned short u) {
    union { unsigned int i; float f; } v; v.i = ((unsigned int)u) << 16; return v.f;
}
__device__ __forceinline__ float wave_sum(float v) {
    #pragma unroll
    for (int o = 32; o; o >>= 1) v += __shfl_down(v, o, 64);
    return v;
}
// butterfly reduce: result valid in ALL lanes (no LDS broadcast needed)
__device__ __forceinline__ float wave_sum_all(float v) {
    #pragma unroll
    for (int o = 32; o; o >>= 1) v += __shfl_xor(v, o, 64);
    return v;
}
__device__ __forceinline__ void async16(const void* g, void* l) {
    __builtin_amdgcn_global_load_lds(
        (const __attribute__((address_space(1))) unsigned int*)g,
        (__attribute__((address_space(3))) unsigned int*)l, 16, 0, 0);
}
__device__ __forceinline__ float sigmoidf(float x) { return 1.f / (1.f + expf(-x)); }
__device__ __forceinline__ float siluf(float x)    { return x / (1.f + expf(-x)); }

// ---------------------------------------------------------------------------
// K0: fused fp32 -> bf16 conversion of all six tensors (1 launch)
// ---------------------------------------------------------------------------
__global__ __launch_bounds__(256) void cvt_all(
    const float* __restrict__ x,  const float* __restrict__ qw,
    const float* __restrict__ kw, const float* __restrict__ vw,
    const float* __restrict__ gw, const float* __restrict__ ow,
    unsigned short* __restrict__ xb, unsigned short* __restrict__ wb,
    unsigned short* __restrict__ owb)
{
    int i = blockIdx.x * 256 + threadIdx.x;
    const float* src; unsigned short* dst; int local;
    if      (i < 1048576) { src = x;  dst = xb;               local = i; }
    else if (i < 1572864) { src = qw; dst = wb;               local = i - 1048576; }
    else if (i < 2097152) { src = kw; dst = wb + 1024 * CHID; local = i - 1572864; }
    else if (i < 3145728) { src = vw; dst = wb + 2048 * CHID; local = i - 2097152; }
    else if (i < 4194304) { src = gw; dst = wb + 4096 * CHID; local = i - 3145728; }
    else                  { src = ow; dst = owb;              local = i - 4194304; }
    f32x4 v = *(const f32x4*)(src + (size_t)local * 4);
    us4 o;
    o.x = f2bf(v.x); o.y = f2bf(v.y); o.z = f2bf(v.z); o.w = f2bf(v.w);
    *(us4*)(dst + (size_t)local * 4) = o;
}

// ---------------------------------------------------------------------------
// K1: per-token small projections + routing + decay (stores LOG decay)
// ---------------------------------------------------------------------------
__global__ __launch_bounds__(256) void prep_kernel(
    const float* __restrict__ x,
    const float* __restrict__ gate_w,
    const float* __restrict__ b_w,
    const float* __restrict__ a_w,
    const float* __restrict__ A_log,
    const float* __restrict__ dt_bias,
    int*   __restrict__ tok_sel,
    float* __restrict__ tok_w,
    float* __restrict__ tok_beta,
    float* __restrict__ tok_glog)
{
    int t = blockIdx.x, tid = threadIdx.x;
    float acc[16];
    #pragma unroll
    for (int r = 0; r < 16; r++) acc[r] = 0.f;
    #pragma unroll
    for (int kk = 0; kk < 2; kk++) {
        int k = (kk * 256 + tid) * 4;
        f32x4 xv = *(const f32x4*)(x + (size_t)t * CHID + k);
        #pragma unroll
        for (int r = 0; r < 8; r++) {
            f32x4 w = *(const f32x4*)(gate_w + (size_t)r * CHID + k);
            acc[r] += xv[0]*w[0] + xv[1]*w[1] + xv[2]*w[2] + xv[3]*w[3];
        }
        #pragma unroll
        for (int r = 0; r < 4; r++) {
            f32x4 w = *(const f32x4*)(b_w + (size_t)r * CHID + k);
            acc[8 + r] += xv[0]*w[0] + xv[1]*w[1] + xv[2]*w[2] + xv[3]*w[3];
        }
        #pragma unroll
        for (int r = 0; r < 4; r++) {
            f32x4 w = *(const f32x4*)(a_w + (size_t)r * CHID + k);
            acc[12 + r] += xv[0]*w[0] + xv[1]*w[1] + xv[2]*w[2] + xv[3]*w[3];
        }
    }
    __shared__ float part[4][16];
    __shared__ float fin[16];
    int lane = tid & 63, wave = tid >> 6;
    #pragma unroll
    for (int r = 0; r < 16; r++) {
        float v = wave_sum(acc[r]);
        if (lane == 0) part[wave][r] = v;
    }
    __syncthreads();
    if (tid < 16) fin[tid] = part[0][tid] + part[1][tid] + part[2][tid] + part[3][tid];
    __syncthreads();
    if (tid == 0) {
        float p[8], mx = -1e30f;
        for (int i = 0; i < 8; i++) { p[i] = fin[i]; if (p[i] > mx) mx = p[i]; }
        float sum = 0.f;
        for (int i = 0; i < 8; i++) { p[i] = expf(p[i] - mx); sum += p[i]; }
        for (int i = 0; i < 8; i++) p[i] /= sum;
        int i0 = 0; float b0 = p[0];
        for (int i = 1; i < 8; i++) if (p[i] > b0) { b0 = p[i]; i0 = i; }
        int i1 = -1; float b1 = -1e30f;
        for (int i = 0; i < 8; i++) { if (i == i0) continue; if (p[i] > b1) { b1 = p[i]; i1 = i; } }
        float wsn = b0 + b1;
        tok_sel[t * 2 + 0] = i0;       tok_sel[t * 2 + 1] = i1;
        tok_w[t * 2 + 0]   = b0 / wsn; tok_w[t * 2 + 1]   = b1 / wsn;
        for (int h = 0; h < 4; h++) {
            float beta = sigmoidf(fin[8 + h]);
            float ar   = fin[12 + h] + dt_bias[h];
            float sp   = (ar > 20.f) ? ar : log1pf(expf(ar));
            float g    = -expf(A_log[h]) * sp;
            tok_beta[t * 4 + h] = beta;
            tok_glog[t * 4 + h] = g;
        }
    }
}

// ---------------------------------------------------------------------------
// K2: build per-(b,m) ordered routed-token lists. grid = 32, block = 512
// ---------------------------------------------------------------------------
__global__ __launch_bounds__(512) void compact_kernel(
    const int* __restrict__ tok_sel, const float* __restrict__ tok_w,
    int* __restrict__ cnt, int* __restrict__ lists, float* __restrict__ wlists)
{
    int p = blockIdx.x;
    int b = p >> 3, m = p & 7;
    int s = threadIdx.x;
    int tok = b * CS + s;
    int s0 = tok_sel[tok * 2 + 0], s1 = tok_sel[tok * 2 + 1];
    int slot = (s0 == m) ? 0 : ((s1 == m) ? 1 : -1);
    bool routed = slot >= 0;
    unsigned long long mask = __ballot(routed);
    int lane = s & 63, wave = s >> 6;
    int pfx = __popcll(mask & ((1ull << lane) - 1ull));
    __shared__ int wcnt[8], woff[8];
    if (lane == 0) wcnt[wave] = (int)__popcll(mask);
    __syncthreads();
    if (threadIdx.x == 0) {
        int o = 0;
        for (int i = 0; i < 8; i++) { woff[i] = o; o += wcnt[i]; }
        cnt[p] = o;
    }
    __syncthreads();
    if (routed) {
        int pos = woff[wave] + pfx;
        lists[p * CS + pos]  = s | (slot << 16);
        wlists[p * CS + pos] = tok_w[tok * 2 + slot];
    }
}

// ---------------------------------------------------------------------------
// K2b: exclusive prefix of ceil(cnt/32) over the 32 (b,m) pairs.
// ---------------------------------------------------------------------------
__global__ __launch_bounds__(64) void chunk_off_kernel(
    const int* __restrict__ cnt, int* __restrict__ coff)
{
    int t = threadIdx.x;
    if (t >= 32) return;
    int c = (cnt[t] + 31) >> 5;
    int s = c;
    #pragma unroll
    for (int o = 1; o < 32; o <<= 1) { int x = __shfl_up(s, o, 64); if (t >= o) s += x; }
    coff[t] = s - c;
    if (t == 31) coff[32] = s;
}

// ---------------------------------------------------------------------------
// K3: fused bf16 GEMM  Cb[T][6144] = x[T][2048] @ Wfused^T   (fp32 out)
// RETILED to the PROVEN gemm_o structure: 128x128 tile, BK=64, 256 threads,
// double-buffered 64 KB LDS (2 blocks/CU vs prior 112 KB = 1 block/CU),
// XOR swizzle both-sides, 1 barrier per K-tile. Grid = 768 (16m x 48n),
// bijective XCD swizzle (768 % 8 == 0, 96 wgs/XCD).
// Guide tile-space (m103/m112): 128^2 = 912 TF > bigger tiles at this
// 2-barrierless dbuf structure.
// ---------------------------------------------------------------------------
__global__ __launch_bounds__(256) void gemm_qkvg(
    const unsigned short* __restrict__ X,
    const unsigned short* __restrict__ Wf,
    float* __restrict__ Cb)
{
    int id = blockIdx.x;
    int wg = (id & 7) * 96 + (id >> 3);   // XCD swizzle (768 % 8 == 0)
    int m0 = (wg & 15) * 128;             // 16 m-tiles
    int n0 = (wg >> 4) * 128;             // 48 n-tiles

    __shared__ __align__(16) unsigned short As[2][128 * 64];  // 2 x 16 KB
    __shared__ __align__(16) unsigned short Bs[2][128 * 64];  // 2 x 16 KB

    int tid = threadIdx.x;
    int wv = tid >> 6, lane = tid & 63;
    int wr = wv >> 1, wn = wv & 1;        // 2 x 2 wave grid, 64x64 per wave
    int lrow = lane & 15, quad = lane >> 4;

    f32x4 acc[4][4];
    #pragma unroll
    for (int i = 0; i < 4; i++)
        #pragma unroll
        for (int j = 0; j < 4; j++) { f32x4 z = {0.f,0.f,0.f,0.f}; acc[i][j] = z; }

    int wbase = (tid & ~63);

    #define STAGE_QKVG(d, kt)                                                   \
    {                                                                           \
        int kb = (kt) * 64;                                                     \
        _Pragma("unroll")                                                       \
        for (int i = 0; i < 4; i++) {                                           \
            int c = i * 256 + tid;                                              \
            int r = c >> 3, cbk = (c & 7) ^ (r & 7);                            \
            async16(X + (size_t)(m0 + r) * CHID + kb + cbk * 8,                 \
                    &As[d][(i * 256 + wbase) * 8]);                             \
            async16(Wf + (size_t)(n0 + r) * CHID + kb + cbk * 8,                \
                    &Bs[d][(i * 256 + wbase) * 8]);                             \
        }                                                                       \
    }

    STAGE_QKVG(0, 0);
    __syncthreads();

    for (int kt = 0; kt < 32; kt++) {
        int cur = kt & 1;
        if (kt < 31) STAGE_QKVG(cur ^ 1, kt + 1);

        #pragma unroll
        for (int ks = 0; ks < 2; ks++) {
            bf16x8 af[4], bfr[4];
            #pragma unroll
            for (int mf = 0; mf < 4; mf++) {
                int row = wr * 64 + mf * 16 + lrow;
                af[mf] = *(const bf16x8*)(&As[cur][row * 64 + (((ks * 4 + quad) ^ (row & 7)) * 8)]);
            }
            #pragma unroll
            for (int nf = 0; nf < 4; nf++) {
                int row = wn * 64 + nf * 16 + lrow;
                bfr[nf] = *(const bf16x8*)(&Bs[cur][row * 64 + (((ks * 4 + quad) ^ (row & 7)) * 8)]);
            }
            #pragma unroll
            for (int mf = 0; mf < 4; mf++)
                #pragma unroll
                for (int nf = 0; nf < 4; nf++)
                    acc[mf][nf] = __builtin_amdgcn_mfma_f32_16x16x32_bf16(af[mf], bfr[nf], acc[mf][nf], 0, 0, 0);
        }
        __syncthreads();
    }
    #undef STAGE_QKVG

    #pragma unroll
    for (int mf = 0; mf < 4; mf++)
        #pragma unroll
        for (int nf = 0; nf < 4; nf++) {
            int gn = n0 + wn * 64 + nf * 16 + lrow;
            #pragma unroll
            for (int r = 0; r < 4; r++) {
                int gm = m0 + wr * 64 + mf * 16 + quad * 4 + r;
                Cb[(size_t)gm * CN4 + gn] = acc[mf][nf][r];
            }
        }
}

// ---------------------------------------------------------------------------
// K4: activations: silu+l2norm on q,k -> qkbf (bf16).
// v-silu lives in chunk_pre (the only consumer of v) — Cb keeps RAW v.
// wave h owns q[h]/k[h]; butterfly reduce; zero barriers.
// ---------------------------------------------------------------------------
__global__ __launch_bounds__(256) void act_qkv(const float* __restrict__ Cb,
                                               unsigned short* __restrict__ qkbf)
{
    int t = blockIdx.x, tid = threadIdx.x;
    int lane = tid & 63, h = tid >> 6;

    size_t base = (size_t)t * CN4 + h * 256 + lane * 4;
    f32x4 qv = *(const f32x4*)(Cb + base);
    f32x4 kv = *(const f32x4*)(Cb + base + 1024);
    f32x4 sq, sk;
    float ssq = 0.f, ssk = 0.f;
    #pragma unroll
    for (int r = 0; r < 4; r++) {
        sq[r] = siluf(qv[r]); ssq += sq[r] * sq[r];
        sk[r] = siluf(kv[r]); ssk += sk[r] * sk[r];
    }
    ssq = wave_sum_all(ssq);
    ssk = wave_sum_all(ssk);
    float qs = 0.0625f / fmaxf(sqrtf(ssq), 1e-12f);
    float ks = 1.f     / fmaxf(sqrtf(ssk), 1e-12f);
    us4 oq, ok;
    #pragma unroll
    for (int r = 0; r < 4; r++) { oq[r] = f2bf(sq[r] * qs); ok[r] = f2bf(sk[r] * ks); }
    *(us4*)(qkbf + ((size_t)t * 4 + h) * 512 + lane * 4)       = oq;
    *(us4*)(qkbf + ((size_t)t * 4 + h) * 512 + 256 + lane * 4) = ok;
}

// ---------------------------------------------------------------------------
// K4b: chunk_pre — h-INDEPENDENT per-chunk algebra, fully parallel.
// Register-unrolled M-inversion (static indexing), Wv via MFMA.
// ---------------------------------------------------------------------------
__global__ __launch_bounds__(256) void chunk_pre(
    const unsigned short* __restrict__ qkbf,
    const float* __restrict__ Cb,
    const float* __restrict__ tok_beta, const float* __restrict__ tok_glog,
    const int* __restrict__ cnt, const int* __restrict__ coff,
    const int* __restrict__ lists,
    unsigned short* __restrict__ Wvg, unsigned short* __restrict__ Sgg,
    unsigned short* __restrict__ M2g, float* __restrict__ ginfo)
{
    int p = blockIdx.x, c = blockIdx.y, h = blockIdx.z;
    int n = cnt[p];
    if (c * 32 >= n) return;
    int b = p >> 3;
    int c0 = c * 32;
    size_t inst = (size_t)((coff[p] + c) * 4 + h);

    // pool: [0,16384) shorts = kq (staged k|q, 32 KB) -> later bvt[512][32]
    //       [16384,20608) shorts = G as float[64][33] (8448 B)
    __shared__ __align__(16) unsigned short pool[20608];
    __shared__ __align__(16) float BA[32][36];
    __shared__ float Mi[32][33];
    __shared__ __align__(16) unsigned short Mb[32 * 32];   // bf16 M, row-major
    __shared__ float sLg[32], sBeta[32], sGam[32];
    __shared__ int   sTok[32];

    unsigned short* kq  = pool;
    float*          G   = (float*)(pool + 16384);          // [64][33]
    unsigned short* bvt = pool;                            // [512][32] (kq dead)

    int tid = threadIdx.x;
    int wv = tid >> 6, lane = tid & 63;
    int lrow = lane & 15, quad = lane >> 4;

    // ---- phase A: stage k|q (tokens read per-thread) + meta scan ----
    #pragma unroll
    for (int r = 0; r < 8; r++) {
        int L = r * 256 + tid;
        int t = L >> 6, sl = L & 63;
        int idx = c0 + t; if (idx >= n) idx = n - 1;
        int e = lists[p * CS + idx];
        int tok = b * CS + (e & 0xffff);
        int slog = ((sl & 31) ^ (t & 31)) | (sl & 32);
        int off = (slog < 32) ? (256 + slog * 8) : ((slog - 32) * 8);
        async16(qkbf + ((size_t)tok * 4 + h) * 512 + off, kq + (size_t)(L & ~63) * 8);
    }
    if (tid < 32) {
        int t = tid;
        int idx = c0 + t;
        bool valid = idx < n;
        int eidx = valid ? idx : (n - 1);
        int e = lists[p * CS + eidx];
        int tok = b * CS + (e & 0xffff);
        sTok[t]  = tok;
        float bt = valid ? tok_beta[tok * 4 + h] : 0.f;
        sBeta[t] = bt;
        float g  = valid ? tok_glog[tok * 4 + h] : 0.f;
        #pragma unroll
        for (int o = 1; o < 32; o <<= 1) {
            float xg = __shfl_up(g, o, 64);
            if (t >= o) g += xg;
        }
        sLg[t]  = g;
        sGam[t] = __expf(g);
        float l31 = __shfl(g, 31, 64);
        ginfo[inst * 64 + t]      = __expf(g);
        ginfo[inst * 64 + 32 + t] = __expf(l31 - g);
    }
    __syncthreads();                                       // (1) kq + meta ready

    // ---- phase B: Gram [K;Q] @ K^T ----
    {
        int mt = wv;
        int trow = (mt & 1) * 16 + lrow;
        int qflag = (mt >= 2) ? 32 : 0;
        #pragma unroll
        for (int nt = 0; nt < 2; nt++) {
            int bcol = nt * 16 + lrow;
            f32x4 g0 = {0.f,0.f,0.f,0.f};
            #pragma unroll
            for (int ks = 0; ks < 8; ks++) {
                int sA = ((ks * 4 + quad) ^ trow) | qflag;
                int sB = (ks * 4 + quad) ^ (bcol & 31);
                bf16x8 af = *(const bf16x8*)(kq + trow * 512 + sA * 8);
                bf16x8 bf = *(const bf16x8*)(kq + bcol * 512 + sB * 8);
                g0 = __builtin_amdgcn_mfma_f32_16x16x32_bf16(af, bf, g0, 0, 0, 0);
            }
            #pragma unroll
            for (int r = 0; r < 4; r++)
                G[(mt * 16 + quad * 4 + r) * 33 + nt * 16 + lrow] = g0[r];
        }
    }
    __syncthreads();                                       // (2) G ready; kq dead

    // ---- phase C: BA build (G lo) + S store (G hi) ----
    for (int idx = tid; idx < 32 * 36; idx += 256) {
        int t = idx / 36, j = idx % 36;
        float v = 0.f;
        if (j < t) v = sBeta[t] * __expf(sLg[t] - sLg[j]) * G[t * 33 + j];
        BA[t][j] = v;
    }
    for (int idx = tid; idx < 1024; idx += 256) {
        int t = idx >> 5, j = idx & 31;
        float sv = (j <= t) ? __expf(sLg[t] - sLg[j]) * G[(32 + t) * 33 + j] : 0.f;
        Sgg[inst * 1024 + idx] = f2bf(sv);
    }
    __syncthreads();                                       // (3) BA ready; G dead

    // ---- phase D: register-unrolled M-inv (tid<32) || bvt staging+silu ----
    if (tid < 32) {
        int j = tid;
        float mcol[32];
        #pragma unroll
        for (int k = 0; k < 32; k++) mcol[k] = (k == j) ? 1.f : 0.f;
        #pragma unroll
        for (int t = 1; t < 32; t++) {
            float acc = 0.f;
            #pragma unroll
            for (int k4 = 0; k4 * 4 < t; k4++) {
                f32x4 ba = *(const f32x4*)&BA[t][k4 * 4];
                #pragma unroll
                for (int e = 0; e < 4; e++)
                    if (k4 * 4 + e < t) acc += ba[e] * mcol[k4 * 4 + e];
            }
            if (t > j) mcol[t] = -acc;
        }
        #pragma unroll
        for (int t = 0; t < 32; t++) Mi[t][j] = mcol[t];
    } else {
        for (int idx = tid - 32; idx < 4096; idx += 224) {
            int t = idx & 31, vg = idx >> 5;
            f32x4 vvv = *(const f32x4*)(Cb + (size_t)sTok[t] * CN4 + 2048 + h * 512 + vg * 4);
            float bt = sBeta[t];
            bvt[(vg * 4 + 0) * 32 + t] = f2bf(bt * siluf(vvv.x));
            bvt[(vg * 4 + 1) * 32 + t] = f2bf(bt * siluf(vvv.y));
            bvt[(vg * 4 + 2) * 32 + t] = f2bf(bt * siluf(vvv.z));
            bvt[(vg * 4 + 3) * 32 + t] = f2bf(bt * siluf(vvv.w));
        }
    }
    __syncthreads();                                       // (4) Mi + bvt ready

    // ---- phase E: M2 store + Mb (bf16 M) build ----
    for (int idx = tid; idx < 1024; idx += 256) {
        int t = idx >> 5, j = idx & 31;
        float mv = (j < t) ? Mi[t][j] : ((j == t) ? 1.f : 0.f);
        M2g[inst * 1024 + idx] = f2bf(-mv * sBeta[j] * sGam[j]);
        Mb[idx] = f2bf(mv);
    }
    __syncthreads();                                       // (5) Mb ready

    // ---- phase F: Wv = M @ bv via MFMA (wave wv: v-cols wv*128..+127) ----
    {
        bf16x8 aT = *(const bf16x8*)(Mb + lrow * 32 + quad * 8);         // M rows 0-15
        bf16x8 aB = *(const bf16x8*)(Mb + (16 + lrow) * 32 + quad * 8);  // M rows 16-31
        #pragma unroll
        for (int tile = 0; tile < 8; tile++) {
            int vcol = wv * 128 + tile * 16 + lrow;
            bf16x8 bf = *(const bf16x8*)(bvt + vcol * 32 + quad * 8);
            f32x4 dT = {0.f,0.f,0.f,0.f}, dB = {0.f,0.f,0.f,0.f};
            dT = __builtin_amdgcn_mfma_f32_16x16x32_bf16(aT, bf, dT, 0, 0, 0);
            dB = __builtin_amdgcn_mfma_f32_16x16x32_bf16(aB, bf, dB, 0, 0, 0);
            unsigned short* wrow = Wvg + inst * 16384 + vcol;
            #pragma unroll
            for (int r = 0; r < 4; r++) {
                wrow[(size_t)(quad * 4 + r) * 512]        = f2bf(dT[r]);
                wrow[(size_t)(16 + quad * 4 + r) * 512]   = f2bf(dB[r]);
            }
        }
    }
}

// ---------------------------------------------------------------------------
// K5: CHUNKED gated delta rule — SERIAL PART ONLY.
// Barrier-drain hygiene: no barrier ever drains a freshly-issued load.
//   - Wv (HBM-cold) software-pipelined one chunk ahead (epilogue issue).
//   - M2g/Sgg/ginfo (L2-hot) issued AFTER barrier B; latency hides under pq.
//   - chunk 0: pq==0 identically (h0=0) -> skip the 32 pq MFMAs + LDS RTs.
// ---------------------------------------------------------------------------
__global__ __launch_bounds__(512) void recur_kernel(
    const unsigned short* __restrict__ qkbf,
    const int* __restrict__ cnt, const int* __restrict__ coff,
    const int* __restrict__ lists, const float* __restrict__ wlists,
    const unsigned short* __restrict__ Wvg, const unsigned short* __restrict__ Sgg,
    const unsigned short* __restrict__ M2g, const float* __restrict__ ginfo,
    float* __restrict__ oslot)
{
    int bx = blockIdx.x;
    int m = bx & 7, b = (bx >> 3) & 3, h = (bx >> 5) & 3, qt = (bx >> 7) & 3;
    int p = b * 8 + m;
    int n = cnt[p];
    int binst = coff[p] * 4 + h;
    int vq = qt * 128;
    int nc = (n + 31) >> 5;

    int tid = threadIdx.x;
    int wv = tid >> 6, lane = tid & 63;
    int lrow = lane & 15, quad = lane >> 4;

    __shared__ __align__(16) unsigned short kq[32 * 512];      // 32 KB swizzled k|q
    __shared__ __align__(16) unsigned short scratch[8 * 1280]; // 20 KB per-wave hb / pB+uB
    __shared__ __align__(16) unsigned short KtS[256 * 40];     // 20 KB K^T [feat][t]

    f32x4 hacc[16];
    #pragma unroll
    for (int i = 0; i < 16; i++) { f32x4 z = {0.f,0.f,0.f,0.f}; hacc[i] = z; }

    // stage chunk c0v's k|q into kq (async16, xor-swizzle)
    #define STAGE_R(c0v)                                                        \
    {                                                                           \
        _Pragma("unroll")                                                       \
        for (int r = 0; r < 4; r++) {                                           \
            int L = r * 512 + tid;                                              \
            int t = L >> 6, sl = L & 63;                                        \
            int idx = (c0v) + t; if (idx >= n) idx = n - 1;                     \
            int e = lists[p * CS + idx];                                        \
            int tok = b * CS + (e & 0xffff);                                    \
            int slog = ((sl & 31) ^ (t & 31)) | (sl & 32);                      \
            int off = (slog < 32) ? (256 + slog * 8) : ((slog - 32) * 8);       \
            async16(qkbf + ((size_t)tok * 4 + h) * 512 + off,                   \
                    kq + (size_t)(L & ~63) * 8);                                \
        }                                                                       \
    }

    // Wv pipeline: load chunk instv's Wv into f32x4 pair (HBM-cold; issued
    // far ahead of the barrier that could drain it)
    #define LOADWV(instv, dA, dB)                                               \
    {                                                                           \
        const unsigned short* wr0 = Wvg + ((size_t)(instv) << 14)               \
            + (size_t)(quad * 4) * 512 + vq + wv * 16 + lrow;                   \
        const unsigned short* wr1 = wr0 + 16 * 512;                             \
        _Pragma("unroll")                                                       \
        for (int r = 0; r < 4; r++) { dA[r] = bf2f(wr0[r * 512]); }             \
        _Pragma("unroll")                                                       \
        for (int r = 0; r < 4; r++) { dB[r] = bf2f(wr1[r * 512]); }             \
    }

    f32x4 wvA, wvB;
    if (nc > 0) {
        STAGE_R(0);
        LOADWV(binst, wvA, wvB);
    }

    for (int cc = 0; cc < nc; cc++) {
        int c0 = cc * 32;
        size_t inst = (size_t)(binst + cc * 4);

        __syncthreads();                              // (B) kq staged; drains only OLD loads

        // ---- small L2-hot operand loads issued post-barrier (consumed in epilogue) ----
        bf16x8 m2f0 = *(const bf16x8*)(M2g + (inst << 10) + (0  + lrow) * 32 + quad * 8);
        bf16x8 m2f1 = *(const bf16x8*)(M2g + (inst << 10) + (16 + lrow) * 32 + quad * 8);
        bf16x8 sf0  = *(const bf16x8*)(Sgg + (inst << 10) + (0  + lrow) * 32 + quad * 8);
        bf16x8 sf1  = *(const bf16x8*)(Sgg + (inst << 10) + (16 + lrow) * 32 + quad * 8);
        f32x4 gm0 = *(const f32x4*)(ginfo + (inst << 6) + quad * 4);
        f32x4 gm1 = *(const f32x4*)(ginfo + (inst << 6) + 16 + quad * 4);
        float gC  = ginfo[(inst << 6) + 31];
        f32x4 rs0 = *(const f32x4*)(ginfo + (inst << 6) + 32 + quad * 8);
        f32x4 rs1 = *(const f32x4*)(ginfo + (inst << 6) + 36 + quad * 8);

        // ---- pq = [K;Q] @ h0 (skip on chunk 0: h0 == 0 -> pq == 0) ----
        f32x4 pq[4];
        #pragma unroll
        for (int i = 0; i < 4; i++) { f32x4 z = {0.f,0.f,0.f,0.f}; pq[i] = z; }
        if (cc > 0) {
            unsigned short* hb = scratch + wv * 1280;
            #pragma unroll
            for (int ph = 0; ph < 4; ph++) {
                #pragma unroll
                for (int mi4 = 0; mi4 < 4; mi4++) {
                    f32x4 hv = hacc[ph * 4 + mi4];
                    us4 pk;
                    pk.x = f2bf(hv.x); pk.y = f2bf(hv.y); pk.z = f2bf(hv.z); pk.w = f2bf(hv.w);
                    *(us4*)(hb + lrow * 68 + mi4 * 16 + quad * 4) = pk;
                }
                #pragma unroll
                for (int ks4 = 0; ks4 < 2; ks4++) {
                    bf16x8 b0 = *(const bf16x8*)(hb + lrow * 68 + ks4 * 32 + quad * 8);
                    int segbase = ph * 8 + ks4 * 4 + quad;
                    #pragma unroll
                    for (int mi = 0; mi < 4; mi++) {
                        int trow = (mi & 1) * 16 + lrow;
                        int sA = (segbase ^ trow) | ((mi >= 2) ? 32 : 0);
                        bf16x8 af = *(const bf16x8*)(kq + trow * 512 + sA * 8);
                        pq[mi] = __builtin_amdgcn_mfma_f32_16x16x32_bf16(af, b0, pq[mi], 0, 0, 0);
                    }
                }
            }
        }

        // ---- Kt = K^T ([feat][t], stride 40) from swizzled kq ----
        {
            int tl = tid & 31, kseg = tid >> 5;
            #pragma unroll
            for (int j8 = 0; j8 < 2; j8++) {
                int slot = (kseg * 2 + j8) ^ tl;
                us8 kv = *(const us8*)(kq + tl * 512 + slot * 8);
                #pragma unroll
                for (int e = 0; e < 8; e++)
                    KtS[(kseg * 16 + j8 * 8 + e) * 40 + tl] = kv[e];
            }
        }
        __syncthreads();                              // (C) kq dead, KtS ready

        // ---- prefetch next chunk's k|q + Wv (hides under epilogue) ----
        f32x4 wvAn, wvBn;
        if (cc + 1 < nc) {
            STAGE_R(c0 + 32);
            LOADWV(inst + 4, wvAn, wvBn);
        }

        // ---- u = Wv + M2neg @ pred  (pred = pq[0..1], via per-wave LDS) ----
        unsigned short* pB = scratch + wv * 1280;     // [16 v][40] (overlays hb, dead)
        unsigned short* uB = pB + 640;                // [16 v][40]
        #pragma unroll
        for (int mi = 0; mi < 2; mi++)
            #pragma unroll
            for (int r = 0; r < 4; r++)
                pB[lrow * 40 + mi * 16 + quad * 4 + r] = f2bf(pq[mi][r]);
        bf16x8 pf = *(const bf16x8*)(pB + lrow * 40 + quad * 8);
        f32x4 uacc[2];
        uacc[0] = wvA; uacc[1] = wvB;
        uacc[0] = __builtin_amdgcn_mfma_f32_16x16x32_bf16(m2f0, pf, uacc[0], 0, 0, 0);
        uacc[1] = __builtin_amdgcn_mfma_f32_16x16x32_bf16(m2f1, pf, uacc[1], 0, 0, 0);
        #pragma unroll
        for (int mi = 0; mi < 2; mi++)
            #pragma unroll
            for (int r = 0; r < 4; r++)
                uB[lrow * 40 + mi * 16 + quad * 4 + r] = f2bf(uacc[mi][r]);
        bf16x8 wb8 = *(const bf16x8*)(uB + lrow * 40 + quad * 8);

        // ---- o = gamma * (Q@h0) + S@u ; scatter with routing weight ----
        f32x4 oacc[2];
        #pragma unroll
        for (int r = 0; r < 4; r++) oacc[0][r] = gm0[r] * pq[2][r];
        #pragma unroll
        for (int r = 0; r < 4; r++) oacc[1][r] = gm1[r] * pq[3][r];
        oacc[0] = __builtin_amdgcn_mfma_f32_16x16x32_bf16(sf0, wb8, oacc[0], 0, 0, 0);
        oacc[1] = __builtin_amdgcn_mfma_f32_16x16x32_bf16(sf1, wb8, oacc[1], 0, 0, 0);
        #pragma unroll
        for (int mi = 0; mi < 2; mi++)
            #pragma unroll
            for (int r = 0; r < 4; r++) {
                int t = mi * 16 + quad * 4 + r;
                if (c0 + t < n) {
                    int e = lists[p * CS + c0 + t];
                    int tok = b * CS + (e & 0xffff);
                    float W = wlists[p * CS + c0 + t];
                    size_t off = (((size_t)(e >> 16) * CT + tok) * CNH + h) * CHVD
                               + vq + wv * 16 + lrow;
                    oslot[off] = W * oacc[mi][r];
                }
            }

        // ---- h <- gammaC * h + K^T @ (rs * u) ----
        {
            bfu wu; wu.b = wb8;
            us8 sc;
            #pragma unroll
            for (int e = 0; e < 4; e++) sc[e]     = f2bf(bf2f(wu.u[e])     * rs0[e]);
            #pragma unroll
            for (int e = 0; e < 4; e++) sc[4 + e] = f2bf(bf2f(wu.u[4 + e]) * rs1[e]);
            bfu ubu; ubu.u = sc;
            bf16x8 ub = ubu.b;
            __builtin_amdgcn_s_setprio(1);
            #pragma unroll
            for (int mi = 0; mi < 16; mi++) {
                bf16x8 ka = *(const bf16x8*)(KtS + (mi * 16 + lrow) * 40 + quad * 8);
                hacc[mi] *= gC;
                hacc[mi] = __builtin_amdgcn_mfma_f32_16x16x32_bf16(ka, ub, hacc[mi], 0, 0, 0);
            }
            __builtin_amdgcn_s_setprio(0);
        }

        wvA = wvAn; wvB = wvBn;
    }
    #undef STAGE_R
    #undef LOADWV
}

// ---------------------------------------------------------------------------
// K6: combine slots + RMSNorm + sigmoid(gproj) gate -> act bf16
// ---------------------------------------------------------------------------
__global__ __launch_bounds__(256) void act_gate(
    const float* __restrict__ oslot, const float* __restrict__ Cb,
    const float* __restrict__ o_norm_w, unsigned short* __restrict__ actb)
{
    int t = blockIdx.x, tid = threadIdx.x;
    int lane = tid & 63, h = tid >> 6;

    size_t b0 = (((size_t)0 * CT + t) * CNH + h) * CHVD + lane * 8;
    size_t b1 = (((size_t)1 * CT + t) * CNH + h) * CHVD + lane * 8;
    f32x4 s0a = *(const f32x4*)(oslot + b0);
    f32x4 s0b = *(const f32x4*)(oslot + b0 + 4);
    f32x4 s1a = *(const f32x4*)(oslot + b1);
    f32x4 s1b = *(const f32x4*)(oslot + b1 + 4);
    f32x4 va, vb;
    float ss = 0.f;
    #pragma unroll
    for (int r = 0; r < 4; r++) {
        va[r] = s0a[r] + s1a[r]; ss += va[r] * va[r];
        vb[r] = s0b[r] + s1b[r]; ss += vb[r] * vb[r];
    }
    ss = wave_sum_all(ss);
    float rinv = 1.f / sqrtf(ss / 512.f + 1e-6f);

    size_t gb = (size_t)t * CN4 + 4096 + h * CHVD + lane * 8;
    f32x4 ga = *(const f32x4*)(Cb + gb);
    f32x4 gbv = *(const f32x4*)(Cb + gb + 4);
    f32x4 wa = *(const f32x4*)(o_norm_w + lane * 8);
    f32x4 wbv = *(const f32x4*)(o_norm_w + lane * 8 + 4);

    us8 o8;
    #pragma unroll
    for (int r = 0; r < 4; r++) {
        o8[r]     = f2bf(va[r] * rinv * wa[r]  * sigmoidf(ga[r]));
        o8[4 + r] = f2bf(vb[r] * rinv * wbv[r] * sigmoidf(gbv[r]));
    }
    *(us8*)(actb + (size_t)t * CVD + h * CHVD + lane * 8) = o8;
}

// ---------------------------------------------------------------------------
// K7: output GEMM  d_out[T][2048] = act[T][2048] @ o_w^T   (fp32 out)
// 128x128 tile, BK=64, double-buffered 64 KB LDS, XOR swizzle both-sides,
// 1 barrier per K-tile, bijective XCD swizzle. Grid = 256 x 1 (1-D!).
// ---------------------------------------------------------------------------
__global__ __launch_bounds__(256) void gemm_o(
    const unsigned short* __restrict__ A,
    const unsigned short* __restrict__ W,
    float* __restrict__ Out)
{
    int id = blockIdx.x;
    int wg = (id & 7) * 32 + (id >> 3);   // XCD swizzle (256 % 8 == 0)
    int m0 = (wg & 15) * 128;
    int n0 = (wg >> 4) * 128;

    __shared__ __align__(16) unsigned short As[2][128 * 64];  // 2 x 16 KB
    __shared__ __align__(16) unsigned short Bs[2][128 * 64];  // 2 x 16 KB

    int tid = threadIdx.x;
    int wv = tid >> 6, lane = tid & 63;
    int wr = wv >> 1, wn = wv & 1;        // 2 x 2 wave grid, 64x64 per wave
    int lrow = lane & 15, quad = lane >> 4;

    f32x4 acc[4][4];
    #pragma unroll
    for (int i = 0; i < 4; i++)
        #pragma unroll
        for (int j = 0; j < 4; j++) { f32x4 z = {0.f,0.f,0.f,0.f}; acc[i][j] = z; }

    int wbase = (tid & ~63);

    #define STAGE_O(d, kt)                                                      \
    {                                                                           \
        int kb = (kt) * 64;                                                     \
        _Pragma("unroll")                                                       \
        for (int i = 0; i < 4; i++) {                                           \
            int c = i * 256 + tid;                                              \
            int r = c >> 3, cbk = (c & 7) ^ (r & 7);                            \
            async16(A + (size_t)(m0 + r) * CVD + kb + cbk * 8,                  \
                    &As[d][(i * 256 + wbase) * 8]);                             \
            async16(W + (size_t)(n0 + r) * CVD + kb + cbk * 8,                  \
                    &Bs[d][(i * 256 + wbase) * 8]);                             \
        }                                                                       \
    }

    STAGE_O(0, 0);
    __syncthreads();

    for (int kt = 0; kt < 32; kt++) {
        int cur = kt & 1;
        if (kt < 31) STAGE_O(cur ^ 1, kt + 1);

        #pragma unroll
        for (int ks = 0; ks < 2; ks++) {
            bf16x8 af[4], bfr[4];
            #pragma unroll
            for (int mf = 0; mf < 4; mf++) {
                int row = wr * 64 + mf * 16 + lrow;
                af[mf] = *(const bf16x8*)(&As[cur][row * 64 + (((ks * 4 + quad) ^ (row & 7)) * 8)]);
            }
            #pragma unroll
            for (int nf = 0; nf < 4; nf++) {
                int row = wn * 64 + nf * 16 + lrow;
                bfr[nf] = *(const bf16x8*)(&Bs[cur][row * 64 + (((ks * 4 + quad) ^ (row & 7)) * 8)]);
            }
            #pragma unroll
            for (int mf = 0; mf < 4; mf++)
                #pragma unroll
                for (int nf = 0; nf < 4; nf++)
                    acc[mf][nf] = __builtin_amdgcn_mfma_f32_16x16x32_bf16(af[mf], bfr[nf], acc[mf][nf], 0, 0, 0);
        }
        __syncthreads();
    }
    #undef STAGE_O

    #pragma unroll
    for (int mf = 0; mf < 4; mf++)
        #pragma unroll
        for (int nf = 0; nf < 4; nf++) {
            int gn = n0 + wn * 64 + nf * 16 + lrow;
            #pragma unroll
            for (int r = 0; r < 4; r++) {
                int gm = m0 + wr * 64 + mf * 16 + quad * 4 + r;
                Out[(size_t)gm * CHID + gn] = acc[mf][nf][r];
            }
        }
}

// ---------------------------------------------------------------------------
extern "C" void kernel_launch(void* const* d_in, const int* in_sizes, int n_in,
                              void* d_out, int out_size, void* d_ws, size_t ws_size,
                              hipStream_t stream)
{
    const float* x      = (const float*)d_in[0];
    const float* gate_w = (const float*)d_in[1];
    const float* q_w    = (const float*)d_in[2];
    const float* k_w    = (const float*)d_in[3];
    const float* v_w    = (const float*)d_in[4];
    const float* b_w    = (const float*)d_in[5];
    const float* a_w    = (const float*)d_in[6];
    const float* g_w    = (const float*)d_in[7];
    const float* o_w    = (const float*)d_in[8];
    const float* A_log  = (const float*)d_in[9];
    const float* dt_b   = (const float*)d_in[10];
    const float* onw    = (const float*)d_in[11];

    char* ws = (char*)d_ws;
    float*          Cb       = (float*)(ws + 0);                  // 50331648 B
    float*          oslot    = (float*)(ws + 50331648);           // 33554432 B
    unsigned short* actb     = (unsigned short*)(ws + 83886080);  //  8388608 B
    unsigned short* qkbf     = actb;                              // overlay: qkbf dies before actb born
    unsigned short* xb       = (unsigned short*)(ws + 92274688);  //  8388608 B
    unsigned short* wb       = (unsigned short*)(ws + 100663296); // 25165824 B
    unsigned short* owb      = (unsigned short*)(ws + 125829120); //  8388608 B
    int*            tok_sel  = (int*)(ws + 134217728);
    float*          tok_w    = (float*)(ws + 134234112);
    float*          tok_beta = (float*)(ws + 134250496);
    float*          tok_glog = (float*)(ws + 134283264);
    int*            cnt      = (int*)(ws + 134316032);
    int*            lists    = (int*)(ws + 134316160);
    float*          wlists   = (float*)(ws + 134381696);
    // chunk_pre outputs overlay the dead xb+wb window (dead after gemm_qkvg):
    unsigned short* Wvg      = (unsigned short*)(ws + 92274688);  // 640*32KB = 20971520 B
    unsigned short* Sgg      = (unsigned short*)(ws + 113246208); // 640*2KB  =  1310720 B
    unsigned short* M2g      = (unsigned short*)(ws + 114556928); // 640*2KB  =  1310720 B
    float*          ginfo    = (float*)(ws + 115867648);          // 640*256B =   163840 B
    int*            coff     = (int*)(ws + 116031488);            // 132 B

    cvt_all<<<dim3(20480), dim3(256), 0, stream>>>(x, q_w, k_w, v_w, g_w, o_w,
                                                   xb, wb, owb);
    prep_kernel<<<dim3(CT), dim3(256), 0, stream>>>(x, gate_w, b_w, a_w, A_log, dt_b,
                                                    tok_sel, tok_w, tok_beta, tok_glog);
    compact_kernel<<<dim3(CB * CNM), dim3(512), 0, stream>>>(tok_sel, tok_w, cnt, lists, wlists);
    gemm_qkvg<<<dim3(768), dim3(256), 0, stream>>>(xb, wb, Cb);
    chunk_off_kernel<<<dim3(1), dim3(64), 0, stream>>>(cnt, coff);
    act_qkv<<<dim3(CT), dim3(256), 0, stream>>>(Cb, qkbf);
    chunk_pre<<<dim3(32, 16, 4), dim3(256), 0, stream>>>(qkbf, Cb, tok_beta, tok_glog,
                                                         cnt, coff, lists,
                                                         Wvg, Sgg, M2g, ginfo);
    recur_kernel<<<dim3(512), dim3(512), 0, stream>>>(qkbf, cnt, coff, lists, wlists,
                                                      Wvg, Sgg, M2g, ginfo, oslot);
    act_gate<<<dim3(CT), dim3(256), 0, stream>>>(oslot, Cb, onw, actb);
    gemm_o<<<dim3(256), dim3(256), 0, stream>>>(actb, owb, (float*)d_out);
}

// Round 11
// 371.672 us; speedup vs baseline: 1.0546x; 1.0546x over previous
//
#include <hip/hip_runtime.h>
#include <stdint.h>

constexpr int CB   = 4;
constexpr int CS   = 512;
constexpr int CHID = 2048;
constexpr int CNH  = 4;
constexpr int CNM  = 8;
constexpr int CVD  = 2048;   // value dim
constexpr int CHVD = 512;    // per-head value dim
constexpr int CT   = CB * CS;   // 2048 tokens
constexpr int CN4  = 6144;      // q(1024)+k(1024)+v(2048)+g(2048)

typedef __bf16 bf16x8 __attribute__((ext_vector_type(8)));
typedef float  f32x4  __attribute__((ext_vector_type(4)));
typedef unsigned short us4 __attribute__((ext_vector_type(4)));
typedef unsigned short us8 __attribute__((ext_vector_type(8)));

union bfu { us8 u; bf16x8 b; };

__device__ __forceinline__ unsigned short f2bf(float f) {
    union { float f; unsigned int i; } v; v.f = f;
    return (unsigned short)((v.i + 0x7fffu + ((v.i >> 16) & 1u)) >> 16);
}
__device__ __forceinline__ float bf2f(unsigned short u) {
    union { unsigned int i; float f; } v; v.i = ((unsigned int)u) << 16; return v.f;
}
__device__ __forceinline__ float wave_sum(float v) {
    #pragma unroll
    for (int o = 32; o; o >>= 1) v += __shfl_down(v, o, 64);
    return v;
}
// butterfly reduce: result valid in ALL lanes (no LDS broadcast needed)
__device__ __forceinline__ float wave_sum_all(float v) {
    #pragma unroll
    for (int o = 32; o; o >>= 1) v += __shfl_xor(v, o, 64);
    return v;
}
__device__ __forceinline__ void async16(const void* g, void* l) {
    __builtin_amdgcn_global_load_lds(
        (const __attribute__((address_space(1))) unsigned int*)g,
        (__attribute__((address_space(3))) unsigned int*)l, 16, 0, 0);
}
__device__ __forceinline__ float sigmoidf(float x) { return 1.f / (1.f + expf(-x)); }
__device__ __forceinline__ float siluf(float x)    { return x / (1.f + expf(-x)); }

// ---------------------------------------------------------------------------
// K0: fused fp32 -> bf16 conversion of all six tensors (1 launch)
// ---------------------------------------------------------------------------
__global__ __launch_bounds__(256) void cvt_all(
    const float* __restrict__ x,  const float* __restrict__ qw,
    const float* __restrict__ kw, const float* __restrict__ vw,
    const float* __restrict__ gw, const float* __restrict__ ow,
    unsigned short* __restrict__ xb, unsigned short* __restrict__ wb,
    unsigned short* __restrict__ owb)
{
    int i = blockIdx.x * 256 + threadIdx.x;
    const float* src; unsigned short* dst; int local;
    if      (i < 1048576) { src = x;  dst = xb;               local = i; }
    else if (i < 1572864) { src = qw; dst = wb;               local = i - 1048576; }
    else if (i < 2097152) { src = kw; dst = wb + 1024 * CHID; local = i - 1572864; }
    else if (i < 3145728) { src = vw; dst = wb + 2048 * CHID; local = i - 2097152; }
    else if (i < 4194304) { src = gw; dst = wb + 4096 * CHID; local = i - 3145728; }
    else                  { src = ow; dst = owb;              local = i - 4194304; }
    f32x4 v = *(const f32x4*)(src + (size_t)local * 4);
    us4 o;
    o.x = f2bf(v.x); o.y = f2bf(v.y); o.z = f2bf(v.z); o.w = f2bf(v.w);
    *(us4*)(dst + (size_t)local * 4) = o;
}

// ---------------------------------------------------------------------------
// K1: per-token small projections + routing + decay (stores LOG decay)
// ---------------------------------------------------------------------------
__global__ __launch_bounds__(256) void prep_kernel(
    const float* __restrict__ x,
    const float* __restrict__ gate_w,
    const float* __restrict__ b_w,
    const float* __restrict__ a_w,
    const float* __restrict__ A_log,
    const float* __restrict__ dt_bias,
    int*   __restrict__ tok_sel,
    float* __restrict__ tok_w,
    float* __restrict__ tok_beta,
    float* __restrict__ tok_glog)
{
    int t = blockIdx.x, tid = threadIdx.x;
    float acc[16];
    #pragma unroll
    for (int r = 0; r < 16; r++) acc[r] = 0.f;
    #pragma unroll
    for (int kk = 0; kk < 2; kk++) {
        int k = (kk * 256 + tid) * 4;
        f32x4 xv = *(const f32x4*)(x + (size_t)t * CHID + k);
        #pragma unroll
        for (int r = 0; r < 8; r++) {
            f32x4 w = *(const f32x4*)(gate_w + (size_t)r * CHID + k);
            acc[r] += xv[0]*w[0] + xv[1]*w[1] + xv[2]*w[2] + xv[3]*w[3];
        }
        #pragma unroll
        for (int r = 0; r < 4; r++) {
            f32x4 w = *(const f32x4*)(b_w + (size_t)r * CHID + k);
            acc[8 + r] += xv[0]*w[0] + xv[1]*w[1] + xv[2]*w[2] + xv[3]*w[3];
        }
        #pragma unroll
        for (int r = 0; r < 4; r++) {
            f32x4 w = *(const f32x4*)(a_w + (size_t)r * CHID + k);
            acc[12 + r] += xv[0]*w[0] + xv[1]*w[1] + xv[2]*w[2] + xv[3]*w[3];
        }
    }
    __shared__ float part[4][16];
    __shared__ float fin[16];
    int lane = tid & 63, wave = tid >> 6;
    #pragma unroll
    for (int r = 0; r < 16; r++) {
        float v = wave_sum(acc[r]);
        if (lane == 0) part[wave][r] = v;
    }
    __syncthreads();
    if (tid < 16) fin[tid] = part[0][tid] + part[1][tid] + part[2][tid] + part[3][tid];
    __syncthreads();
    if (tid == 0) {
        float p[8], mx = -1e30f;
        for (int i = 0; i < 8; i++) { p[i] = fin[i]; if (p[i] > mx) mx = p[i]; }
        float sum = 0.f;
        for (int i = 0; i < 8; i++) { p[i] = expf(p[i] - mx); sum += p[i]; }
        for (int i = 0; i < 8; i++) p[i] /= sum;
        int i0 = 0; float b0 = p[0];
        for (int i = 1; i < 8; i++) if (p[i] > b0) { b0 = p[i]; i0 = i; }
        int i1 = -1; float b1 = -1e30f;
        for (int i = 0; i < 8; i++) { if (i == i0) continue; if (p[i] > b1) { b1 = p[i]; i1 = i; } }
        float wsn = b0 + b1;
        tok_sel[t * 2 + 0] = i0;       tok_sel[t * 2 + 1] = i1;
        tok_w[t * 2 + 0]   = b0 / wsn; tok_w[t * 2 + 1]   = b1 / wsn;
        for (int h = 0; h < 4; h++) {
            float beta = sigmoidf(fin[8 + h]);
            float ar   = fin[12 + h] + dt_bias[h];
            float sp   = (ar > 20.f) ? ar : log1pf(expf(ar));
            float g    = -expf(A_log[h]) * sp;
            tok_beta[t * 4 + h] = beta;
            tok_glog[t * 4 + h] = g;
        }
    }
}

// ---------------------------------------------------------------------------
// K2: build per-(b,m) ordered routed-token lists. grid = 32, block = 512
// ---------------------------------------------------------------------------
__global__ __launch_bounds__(512) void compact_kernel(
    const int* __restrict__ tok_sel, const float* __restrict__ tok_w,
    int* __restrict__ cnt, int* __restrict__ lists, float* __restrict__ wlists)
{
    int p = blockIdx.x;
    int b = p >> 3, m = p & 7;
    int s = threadIdx.x;
    int tok = b * CS + s;
    int s0 = tok_sel[tok * 2 + 0], s1 = tok_sel[tok * 2 + 1];
    int slot = (s0 == m) ? 0 : ((s1 == m) ? 1 : -1);
    bool routed = slot >= 0;
    unsigned long long mask = __ballot(routed);
    int lane = s & 63, wave = s >> 6;
    int pfx = __popcll(mask & ((1ull << lane) - 1ull));
    __shared__ int wcnt[8], woff[8];
    if (lane == 0) wcnt[wave] = (int)__popcll(mask);
    __syncthreads();
    if (threadIdx.x == 0) {
        int o = 0;
        for (int i = 0; i < 8; i++) { woff[i] = o; o += wcnt[i]; }
        cnt[p] = o;
    }
    __syncthreads();
    if (routed) {
        int pos = woff[wave] + pfx;
        lists[p * CS + pos]  = s | (slot << 16);
        wlists[p * CS + pos] = tok_w[tok * 2 + slot];
    }
}

// ---------------------------------------------------------------------------
// K2b: exclusive prefix of ceil(cnt/32) over the 32 (b,m) pairs.
// ---------------------------------------------------------------------------
__global__ __launch_bounds__(64) void chunk_off_kernel(
    const int* __restrict__ cnt, int* __restrict__ coff)
{
    int t = threadIdx.x;
    if (t >= 32) return;
    int c = (cnt[t] + 31) >> 5;
    int s = c;
    #pragma unroll
    for (int o = 1; o < 32; o <<= 1) { int x = __shfl_up(s, o, 64); if (t >= o) s += x; }
    coff[t] = s - c;
    if (t == 31) coff[32] = s;
}

// ---------------------------------------------------------------------------
// K3: fused bf16 GEMM  Cb[T][6144] = x[T][2048] @ Wfused^T   (fp32 out)
// 256x192 tile, BK=64, 512 threads (8 waves, 2Mx4N), per-wave 128x48 acc.
// LDS double-buffered 112 KB, XOR-swizzled (both-sides), XCD swizzle.
// NOTE (R10 post-mortem): 128^2 retile with 768 blocks REGRESSED (84.9 us,
// FETCH 78 MB vs 33.5 ideal) — halved per-block reuse lost more in L2
// misses than 2-blocks/CU occupancy gained. This 256x192 version (~71 us)
// is the measured optimum for this shape; tile lessons are shape-dependent.
// ---------------------------------------------------------------------------
__global__ __launch_bounds__(512) void gemm_qkvg(
    const unsigned short* __restrict__ X,
    const unsigned short* __restrict__ Wf,
    float* __restrict__ Cb)
{
    int id = blockIdx.x;
    int wg = (id & 7) * 32 + (id >> 3);
    int m0 = (wg & 7) * 256;     // 8 m-tiles
    int n0 = (wg >> 3) * 192;    // 32 n-tiles

    __shared__ __align__(16) unsigned short As[2][256 * 64];  // 2 x 32 KB
    __shared__ __align__(16) unsigned short Bs[2][192 * 64];  // 2 x 24 KB

    int tid = threadIdx.x;
    int wv = tid >> 6, lane = tid & 63;
    int wr = wv >> 2, wn = wv & 3;            // 2 x 4 wave grid
    int lrow = lane & 15, quad = lane >> 4;

    f32x4 acc[8][3];
    #pragma unroll
    for (int i = 0; i < 8; i++)
        #pragma unroll
        for (int j = 0; j < 3; j++) { f32x4 z = {0.f,0.f,0.f,0.f}; acc[i][j] = z; }

    int wbase = (tid & ~63);

    #define STAGE_QKVG(d, kt)                                                   \
    {                                                                           \
        int kb = (kt) * 64;                                                     \
        _Pragma("unroll")                                                       \
        for (int i = 0; i < 4; i++) {                                           \
            int c = i * 512 + tid;                                              \
            int r = c >> 3, cbk = (c & 7) ^ (r & 7);                            \
            async16(X + (size_t)(m0 + r) * CHID + kb + cbk * 8,                 \
                    &As[d][(i * 512 + wbase) * 8]);                             \
        }                                                                       \
        _Pragma("unroll")                                                       \
        for (int i = 0; i < 3; i++) {                                           \
            int c = i * 512 + tid;                                              \
            int r = c >> 3, cbk = (c & 7) ^ (r & 7);                            \
            async16(Wf + (size_t)(n0 + r) * CHID + kb + cbk * 8,                \
                    &Bs[d][(i * 512 + wbase) * 8]);                             \
        }                                                                       \
    }

    STAGE_QKVG(0, 0);
    __syncthreads();

    for (int kt = 0; kt < 32; kt++) {
        int cur = kt & 1;
        if (kt < 31) STAGE_QKVG(cur ^ 1, kt + 1);

        #pragma unroll
        for (int ks = 0; ks < 2; ks++) {
            bf16x8 af[8], bfr[3];
            #pragma unroll
            for (int mf = 0; mf < 8; mf++) {
                int row = wr * 128 + mf * 16 + lrow;
                af[mf] = *(const bf16x8*)(&As[cur][row * 64 + (((ks * 4 + quad) ^ (row & 7)) * 8)]);
            }
            #pragma unroll
            for (int nf = 0; nf < 3; nf++) {
                int row = wn * 48 + nf * 16 + lrow;
                bfr[nf] = *(const bf16x8*)(&Bs[cur][row * 64 + (((ks * 4 + quad) ^ (row & 7)) * 8)]);
            }
            #pragma unroll
            for (int mf = 0; mf < 8; mf++)
                #pragma unroll
                for (int nf = 0; nf < 3; nf++)
                    acc[mf][nf] = __builtin_amdgcn_mfma_f32_16x16x32_bf16(af[mf], bfr[nf], acc[mf][nf], 0, 0, 0);
        }
        __syncthreads();
    }
    #undef STAGE_QKVG

    #pragma unroll
    for (int mf = 0; mf < 8; mf++)
        #pragma unroll
        for (int nf = 0; nf < 3; nf++) {
            int gn = n0 + wn * 48 + nf * 16 + lrow;
            #pragma unroll
            for (int r = 0; r < 4; r++) {
                int gm = m0 + wr * 128 + mf * 16 + quad * 4 + r;
                Cb[(size_t)gm * CN4 + gn] = acc[mf][nf][r];
            }
        }
}

// ---------------------------------------------------------------------------
// K4: activations: silu+l2norm on q,k -> qkbf (bf16).
// v-silu lives in chunk_pre (the only consumer of v) — Cb keeps RAW v.
// wave h owns q[h]/k[h]; butterfly reduce; zero barriers.
// ---------------------------------------------------------------------------
__global__ __launch_bounds__(256) void act_qkv(const float* __restrict__ Cb,
                                               unsigned short* __restrict__ qkbf)
{
    int t = blockIdx.x, tid = threadIdx.x;
    int lane = tid & 63, h = tid >> 6;

    size_t base = (size_t)t * CN4 + h * 256 + lane * 4;
    f32x4 qv = *(const f32x4*)(Cb + base);
    f32x4 kv = *(const f32x4*)(Cb + base + 1024);
    f32x4 sq, sk;
    float ssq = 0.f, ssk = 0.f;
    #pragma unroll
    for (int r = 0; r < 4; r++) {
        sq[r] = siluf(qv[r]); ssq += sq[r] * sq[r];
        sk[r] = siluf(kv[r]); ssk += sk[r] * sk[r];
    }
    ssq = wave_sum_all(ssq);
    ssk = wave_sum_all(ssk);
    float qs = 0.0625f / fmaxf(sqrtf(ssq), 1e-12f);
    float ks = 1.f     / fmaxf(sqrtf(ssk), 1e-12f);
    us4 oq, ok;
    #pragma unroll
    for (int r = 0; r < 4; r++) { oq[r] = f2bf(sq[r] * qs); ok[r] = f2bf(sk[r] * ks); }
    *(us4*)(qkbf + ((size_t)t * 4 + h) * 512 + lane * 4)       = oq;
    *(us4*)(qkbf + ((size_t)t * 4 + h) * 512 + 256 + lane * 4) = ok;
}

// ---------------------------------------------------------------------------
// K4b: chunk_pre — h-INDEPENDENT per-chunk algebra, fully parallel.
// Register-unrolled M-inversion (static indexing), Wv via MFMA.
// ---------------------------------------------------------------------------
__global__ __launch_bounds__(256) void chunk_pre(
    const unsigned short* __restrict__ qkbf,
    const float* __restrict__ Cb,
    const float* __restrict__ tok_beta, const float* __restrict__ tok_glog,
    const int* __restrict__ cnt, const int* __restrict__ coff,
    const int* __restrict__ lists,
    unsigned short* __restrict__ Wvg, unsigned short* __restrict__ Sgg,
    unsigned short* __restrict__ M2g, float* __restrict__ ginfo)
{
    int p = blockIdx.x, c = blockIdx.y, h = blockIdx.z;
    int n = cnt[p];
    if (c * 32 >= n) return;
    int b = p >> 3;
    int c0 = c * 32;
    size_t inst = (size_t)((coff[p] + c) * 4 + h);

    // pool: [0,16384) shorts = kq (staged k|q, 32 KB) -> later bvt[512][32]
    //       [16384,20608) shorts = G as float[64][33] (8448 B)
    __shared__ __align__(16) unsigned short pool[20608];
    __shared__ __align__(16) float BA[32][36];
    __shared__ float Mi[32][33];
    __shared__ __align__(16) unsigned short Mb[32 * 32];   // bf16 M, row-major
    __shared__ float sLg[32], sBeta[32], sGam[32];
    __shared__ int   sTok[32];

    unsigned short* kq  = pool;
    float*          G   = (float*)(pool + 16384);          // [64][33]
    unsigned short* bvt = pool;                            // [512][32] (kq dead)

    int tid = threadIdx.x;
    int wv = tid >> 6, lane = tid & 63;
    int lrow = lane & 15, quad = lane >> 4;

    // ---- phase A: stage k|q (tokens read per-thread) + meta scan ----
    #pragma unroll
    for (int r = 0; r < 8; r++) {
        int L = r * 256 + tid;
        int t = L >> 6, sl = L & 63;
        int idx = c0 + t; if (idx >= n) idx = n - 1;
        int e = lists[p * CS + idx];
        int tok = b * CS + (e & 0xffff);
        int slog = ((sl & 31) ^ (t & 31)) | (sl & 32);
        int off = (slog < 32) ? (256 + slog * 8) : ((slog - 32) * 8);
        async16(qkbf + ((size_t)tok * 4 + h) * 512 + off, kq + (size_t)(L & ~63) * 8);
    }
    if (tid < 32) {
        int t = tid;
        int idx = c0 + t;
        bool valid = idx < n;
        int eidx = valid ? idx : (n - 1);
        int e = lists[p * CS + eidx];
        int tok = b * CS + (e & 0xffff);
        sTok[t]  = tok;
        float bt = valid ? tok_beta[tok * 4 + h] : 0.f;
        sBeta[t] = bt;
        float g  = valid ? tok_glog[tok * 4 + h] : 0.f;
        #pragma unroll
        for (int o = 1; o < 32; o <<= 1) {
            float xg = __shfl_up(g, o, 64);
            if (t >= o) g += xg;
        }
        sLg[t]  = g;
        sGam[t] = __expf(g);
        float l31 = __shfl(g, 31, 64);
        ginfo[inst * 64 + t]      = __expf(g);
        ginfo[inst * 64 + 32 + t] = __expf(l31 - g);
    }
    __syncthreads();                                       // (1) kq + meta ready

    // ---- phase B: Gram [K;Q] @ K^T ----
    {
        int mt = wv;
        int trow = (mt & 1) * 16 + lrow;
        int qflag = (mt >= 2) ? 32 : 0;
        #pragma unroll
        for (int nt = 0; nt < 2; nt++) {
            int bcol = nt * 16 + lrow;
            f32x4 g0 = {0.f,0.f,0.f,0.f};
            #pragma unroll
            for (int ks = 0; ks < 8; ks++) {
                int sA = ((ks * 4 + quad) ^ trow) | qflag;
                int sB = (ks * 4 + quad) ^ (bcol & 31);
                bf16x8 af = *(const bf16x8*)(kq + trow * 512 + sA * 8);
                bf16x8 bf = *(const bf16x8*)(kq + bcol * 512 + sB * 8);
                g0 = __builtin_amdgcn_mfma_f32_16x16x32_bf16(af, bf, g0, 0, 0, 0);
            }
            #pragma unroll
            for (int r = 0; r < 4; r++)
                G[(mt * 16 + quad * 4 + r) * 33 + nt * 16 + lrow] = g0[r];
        }
    }
    __syncthreads();                                       // (2) G ready; kq dead

    // ---- phase C: BA build (G lo) + S store (G hi) ----
    for (int idx = tid; idx < 32 * 36; idx += 256) {
        int t = idx / 36, j = idx % 36;
        float v = 0.f;
        if (j < t) v = sBeta[t] * __expf(sLg[t] - sLg[j]) * G[t * 33 + j];
        BA[t][j] = v;
    }
    for (int idx = tid; idx < 1024; idx += 256) {
        int t = idx >> 5, j = idx & 31;
        float sv = (j <= t) ? __expf(sLg[t] - sLg[j]) * G[(32 + t) * 33 + j] : 0.f;
        Sgg[inst * 1024 + idx] = f2bf(sv);
    }
    __syncthreads();                                       // (3) BA ready; G dead

    // ---- phase D: register-unrolled M-inv (tid<32) || bvt staging+silu ----
    if (tid < 32) {
        int j = tid;
        float mcol[32];
        #pragma unroll
        for (int k = 0; k < 32; k++) mcol[k] = (k == j) ? 1.f : 0.f;
        #pragma unroll
        for (int t = 1; t < 32; t++) {
            float acc = 0.f;
            #pragma unroll
            for (int k4 = 0; k4 * 4 < t; k4++) {
                f32x4 ba = *(const f32x4*)&BA[t][k4 * 4];
                #pragma unroll
                for (int e = 0; e < 4; e++)
                    if (k4 * 4 + e < t) acc += ba[e] * mcol[k4 * 4 + e];
            }
            if (t > j) mcol[t] = -acc;
        }
        #pragma unroll
        for (int t = 0; t < 32; t++) Mi[t][j] = mcol[t];
    } else {
        for (int idx = tid - 32; idx < 4096; idx += 224) {
            int t = idx & 31, vg = idx >> 5;
            f32x4 vvv = *(const f32x4*)(Cb + (size_t)sTok[t] * CN4 + 2048 + h * 512 + vg * 4);
            float bt = sBeta[t];
            bvt[(vg * 4 + 0) * 32 + t] = f2bf(bt * siluf(vvv.x));
            bvt[(vg * 4 + 1) * 32 + t] = f2bf(bt * siluf(vvv.y));
            bvt[(vg * 4 + 2) * 32 + t] = f2bf(bt * siluf(vvv.z));
            bvt[(vg * 4 + 3) * 32 + t] = f2bf(bt * siluf(vvv.w));
        }
    }
    __syncthreads();                                       // (4) Mi + bvt ready

    // ---- phase E: M2 store + Mb (bf16 M) build ----
    for (int idx = tid; idx < 1024; idx += 256) {
        int t = idx >> 5, j = idx & 31;
        float mv = (j < t) ? Mi[t][j] : ((j == t) ? 1.f : 0.f);
        M2g[inst * 1024 + idx] = f2bf(-mv * sBeta[j] * sGam[j]);
        Mb[idx] = f2bf(mv);
    }
    __syncthreads();                                       // (5) Mb ready

    // ---- phase F: Wv = M @ bv via MFMA (wave wv: v-cols wv*128..+127) ----
    {
        bf16x8 aT = *(const bf16x8*)(Mb + lrow * 32 + quad * 8);         // M rows 0-15
        bf16x8 aB = *(const bf16x8*)(Mb + (16 + lrow) * 32 + quad * 8);  // M rows 16-31
        #pragma unroll
        for (int tile = 0; tile < 8; tile++) {
            int vcol = wv * 128 + tile * 16 + lrow;
            bf16x8 bf = *(const bf16x8*)(bvt + vcol * 32 + quad * 8);
            f32x4 dT = {0.f,0.f,0.f,0.f}, dB = {0.f,0.f,0.f,0.f};
            dT = __builtin_amdgcn_mfma_f32_16x16x32_bf16(aT, bf, dT, 0, 0, 0);
            dB = __builtin_amdgcn_mfma_f32_16x16x32_bf16(aB, bf, dB, 0, 0, 0);
            unsigned short* wrow = Wvg + inst * 16384 + vcol;
            #pragma unroll
            for (int r = 0; r < 4; r++) {
                wrow[(size_t)(quad * 4 + r) * 512]        = f2bf(dT[r]);
                wrow[(size_t)(16 + quad * 4 + r) * 512]   = f2bf(dB[r]);
            }
        }
    }
}

// ---------------------------------------------------------------------------
// K5: CHUNKED gated delta rule — SERIAL PART ONLY.
// Barrier-drain hygiene: no barrier ever drains a freshly-issued load.
//   - Wv (HBM-cold) software-pipelined one chunk ahead (epilogue issue).
//   - M2g/Sgg/ginfo (L2-hot) issued AFTER barrier B; latency hides under pq.
//   - chunk 0: pq==0 identically (h0=0) -> skip the 32 pq MFMAs + LDS RTs.
// ---------------------------------------------------------------------------
__global__ __launch_bounds__(512) void recur_kernel(
    const unsigned short* __restrict__ qkbf,
    const int* __restrict__ cnt, const int* __restrict__ coff,
    const int* __restrict__ lists, const float* __restrict__ wlists,
    const unsigned short* __restrict__ Wvg, const unsigned short* __restrict__ Sgg,
    const unsigned short* __restrict__ M2g, const float* __restrict__ ginfo,
    float* __restrict__ oslot)
{
    int bx = blockIdx.x;
    int m = bx & 7, b = (bx >> 3) & 3, h = (bx >> 5) & 3, qt = (bx >> 7) & 3;
    int p = b * 8 + m;
    int n = cnt[p];
    int binst = coff[p] * 4 + h;
    int vq = qt * 128;
    int nc = (n + 31) >> 5;

    int tid = threadIdx.x;
    int wv = tid >> 6, lane = tid & 63;
    int lrow = lane & 15, quad = lane >> 4;

    __shared__ __align__(16) unsigned short kq[32 * 512];      // 32 KB swizzled k|q
    __shared__ __align__(16) unsigned short scratch[8 * 1280]; // 20 KB per-wave hb / pB+uB
    __shared__ __align__(16) unsigned short KtS[256 * 40];     // 20 KB K^T [feat][t]

    f32x4 hacc[16];
    #pragma unroll
    for (int i = 0; i < 16; i++) { f32x4 z = {0.f,0.f,0.f,0.f}; hacc[i] = z; }

    // stage chunk c0v's k|q into kq (async16, xor-swizzle)
    #define STAGE_R(c0v)                                                        \
    {                                                                           \
        _Pragma("unroll")                                                       \
        for (int r = 0; r < 4; r++) {                                           \
            int L = r * 512 + tid;                                              \
            int t = L >> 6, sl = L & 63;                                        \
            int idx = (c0v) + t; if (idx >= n) idx = n - 1;                     \
            int e = lists[p * CS + idx];                                        \
            int tok = b * CS + (e & 0xffff);                                    \
            int slog = ((sl & 31) ^ (t & 31)) | (sl & 32);                      \
            int off = (slog < 32) ? (256 + slog * 8) : ((slog - 32) * 8);       \
            async16(qkbf + ((size_t)tok * 4 + h) * 512 + off,                   \
                    kq + (size_t)(L & ~63) * 8);                                \
        }                                                                       \
    }

    // Wv pipeline: load chunk instv's Wv into f32x4 pair (HBM-cold; issued
    // far ahead of the barrier that could drain it)
    #define LOADWV(instv, dA, dB)                                               \
    {                                                                           \
        const unsigned short* wr0 = Wvg + ((size_t)(instv) << 14)               \
            + (size_t)(quad * 4) * 512 + vq + wv * 16 + lrow;                   \
        const unsigned short* wr1 = wr0 + 16 * 512;                             \
        _Pragma("unroll")                                                       \
        for (int r = 0; r < 4; r++) { dA[r] = bf2f(wr0[r * 512]); }             \
        _Pragma("unroll")                                                       \
        for (int r = 0; r < 4; r++) { dB[r] = bf2f(wr1[r * 512]); }             \
    }

    f32x4 wvA, wvB;
    if (nc > 0) {
        STAGE_R(0);
        LOADWV(binst, wvA, wvB);
    }

    for (int cc = 0; cc < nc; cc++) {
        int c0 = cc * 32;
        size_t inst = (size_t)(binst + cc * 4);

        __syncthreads();                              // (B) kq staged; drains only OLD loads

        // ---- small L2-hot operand loads issued post-barrier (consumed in epilogue) ----
        bf16x8 m2f0 = *(const bf16x8*)(M2g + (inst << 10) + (0  + lrow) * 32 + quad * 8);
        bf16x8 m2f1 = *(const bf16x8*)(M2g + (inst << 10) + (16 + lrow) * 32 + quad * 8);
        bf16x8 sf0  = *(const bf16x8*)(Sgg + (inst << 10) + (0  + lrow) * 32 + quad * 8);
        bf16x8 sf1  = *(const bf16x8*)(Sgg + (inst << 10) + (16 + lrow) * 32 + quad * 8);
        f32x4 gm0 = *(const f32x4*)(ginfo + (inst << 6) + quad * 4);
        f32x4 gm1 = *(const f32x4*)(ginfo + (inst << 6) + 16 + quad * 4);
        float gC  = ginfo[(inst << 6) + 31];
        f32x4 rs0 = *(const f32x4*)(ginfo + (inst << 6) + 32 + quad * 8);
        f32x4 rs1 = *(const f32x4*)(ginfo + (inst << 6) + 36 + quad * 8);

        // ---- pq = [K;Q] @ h0 (skip on chunk 0: h0 == 0 -> pq == 0) ----
        f32x4 pq[4];
        #pragma unroll
        for (int i = 0; i < 4; i++) { f32x4 z = {0.f,0.f,0.f,0.f}; pq[i] = z; }
        if (cc > 0) {
            unsigned short* hb = scratch + wv * 1280;
            #pragma unroll
            for (int ph = 0; ph < 4; ph++) {
                #pragma unroll
                for (int mi4 = 0; mi4 < 4; mi4++) {
                    f32x4 hv = hacc[ph * 4 + mi4];
                    us4 pk;
                    pk.x = f2bf(hv.x); pk.y = f2bf(hv.y); pk.z = f2bf(hv.z); pk.w = f2bf(hv.w);
                    *(us4*)(hb + lrow * 68 + mi4 * 16 + quad * 4) = pk;
                }
                #pragma unroll
                for (int ks4 = 0; ks4 < 2; ks4++) {
                    bf16x8 b0 = *(const bf16x8*)(hb + lrow * 68 + ks4 * 32 + quad * 8);
                    int segbase = ph * 8 + ks4 * 4 + quad;
                    #pragma unroll
                    for (int mi = 0; mi < 4; mi++) {
                        int trow = (mi & 1) * 16 + lrow;
                        int sA = (segbase ^ trow) | ((mi >= 2) ? 32 : 0);
                        bf16x8 af = *(const bf16x8*)(kq + trow * 512 + sA * 8);
                        pq[mi] = __builtin_amdgcn_mfma_f32_16x16x32_bf16(af, b0, pq[mi], 0, 0, 0);
                    }
                }
            }
        }

        // ---- Kt = K^T ([feat][t], stride 40) from swizzled kq ----
        {
            int tl = tid & 31, kseg = tid >> 5;
            #pragma unroll
            for (int j8 = 0; j8 < 2; j8++) {
                int slot = (kseg * 2 + j8) ^ tl;
                us8 kv = *(const us8*)(kq + tl * 512 + slot * 8);
                #pragma unroll
                for (int e = 0; e < 8; e++)
                    KtS[(kseg * 16 + j8 * 8 + e) * 40 + tl] = kv[e];
            }
        }
        __syncthreads();                              // (C) kq dead, KtS ready

        // ---- prefetch next chunk's k|q + Wv (hides under epilogue) ----
        f32x4 wvAn, wvBn;
        if (cc + 1 < nc) {
            STAGE_R(c0 + 32);
            LOADWV(inst + 4, wvAn, wvBn);
        }

        // ---- u = Wv + M2neg @ pred  (pred = pq[0..1], via per-wave LDS) ----
        unsigned short* pB = scratch + wv * 1280;     // [16 v][40] (overlays hb, dead)
        unsigned short* uB = pB + 640;                // [16 v][40]
        #pragma unroll
        for (int mi = 0; mi < 2; mi++)
            #pragma unroll
            for (int r = 0; r < 4; r++)
                pB[lrow * 40 + mi * 16 + quad * 4 + r] = f2bf(pq[mi][r]);
        bf16x8 pf = *(const bf16x8*)(pB + lrow * 40 + quad * 8);
        f32x4 uacc[2];
        uacc[0] = wvA; uacc[1] = wvB;
        uacc[0] = __builtin_amdgcn_mfma_f32_16x16x32_bf16(m2f0, pf, uacc[0], 0, 0, 0);
        uacc[1] = __builtin_amdgcn_mfma_f32_16x16x32_bf16(m2f1, pf, uacc[1], 0, 0, 0);
        #pragma unroll
        for (int mi = 0; mi < 2; mi++)
            #pragma unroll
            for (int r = 0; r < 4; r++)
                uB[lrow * 40 + mi * 16 + quad * 4 + r] = f2bf(uacc[mi][r]);
        bf16x8 wb8 = *(const bf16x8*)(uB + lrow * 40 + quad * 8);

        // ---- o = gamma * (Q@h0) + S@u ; scatter with routing weight ----
        f32x4 oacc[2];
        #pragma unroll
        for (int r = 0; r < 4; r++) oacc[0][r] = gm0[r] * pq[2][r];
        #pragma unroll
        for (int r = 0; r < 4; r++) oacc[1][r] = gm1[r] * pq[3][r];
        oacc[0] = __builtin_amdgcn_mfma_f32_16x16x32_bf16(sf0, wb8, oacc[0], 0, 0, 0);
        oacc[1] = __builtin_amdgcn_mfma_f32_16x16x32_bf16(sf1, wb8, oacc[1], 0, 0, 0);
        #pragma unroll
        for (int mi = 0; mi < 2; mi++)
            #pragma unroll
            for (int r = 0; r < 4; r++) {
                int t = mi * 16 + quad * 4 + r;
                if (c0 + t < n) {
                    int e = lists[p * CS + c0 + t];
                    int tok = b * CS + (e & 0xffff);
                    float W = wlists[p * CS + c0 + t];
                    size_t off = (((size_t)(e >> 16) * CT + tok) * CNH + h) * CHVD
                               + vq + wv * 16 + lrow;
                    oslot[off] = W * oacc[mi][r];
                }
            }

        // ---- h <- gammaC * h + K^T @ (rs * u) ----
        {
            bfu wu; wu.b = wb8;
            us8 sc;
            #pragma unroll
            for (int e = 0; e < 4; e++) sc[e]     = f2bf(bf2f(wu.u[e])     * rs0[e]);
            #pragma unroll
            for (int e = 0; e < 4; e++) sc[4 + e] = f2bf(bf2f(wu.u[4 + e]) * rs1[e]);
            bfu ubu; ubu.u = sc;
            bf16x8 ub = ubu.b;
            __builtin_amdgcn_s_setprio(1);
            #pragma unroll
            for (int mi = 0; mi < 16; mi++) {
                bf16x8 ka = *(const bf16x8*)(KtS + (mi * 16 + lrow) * 40 + quad * 8);
                hacc[mi] *= gC;
                hacc[mi] = __builtin_amdgcn_mfma_f32_16x16x32_bf16(ka, ub, hacc[mi], 0, 0, 0);
            }
            __builtin_amdgcn_s_setprio(0);
        }

        wvA = wvAn; wvB = wvBn;
    }
    #undef STAGE_R
    #undef LOADWV
}

// ---------------------------------------------------------------------------
// K6: combine slots + RMSNorm + sigmoid(gproj) gate -> act bf16
// ---------------------------------------------------------------------------
__global__ __launch_bounds__(256) void act_gate(
    const float* __restrict__ oslot, const float* __restrict__ Cb,
    const float* __restrict__ o_norm_w, unsigned short* __restrict__ actb)
{
    int t = blockIdx.x, tid = threadIdx.x;
    int lane = tid & 63, h = tid >> 6;

    size_t b0 = (((size_t)0 * CT + t) * CNH + h) * CHVD + lane * 8;
    size_t b1 = (((size_t)1 * CT + t) * CNH + h) * CHVD + lane * 8;
    f32x4 s0a = *(const f32x4*)(oslot + b0);
    f32x4 s0b = *(const f32x4*)(oslot + b0 + 4);
    f32x4 s1a = *(const f32x4*)(oslot + b1);
    f32x4 s1b = *(const f32x4*)(oslot + b1 + 4);
    f32x4 va, vb;
    float ss = 0.f;
    #pragma unroll
    for (int r = 0; r < 4; r++) {
        va[r] = s0a[r] + s1a[r]; ss += va[r] * va[r];
        vb[r] = s0b[r] + s1b[r]; ss += vb[r] * vb[r];
    }
    ss = wave_sum_all(ss);
    float rinv = 1.f / sqrtf(ss / 512.f + 1e-6f);

    size_t gb = (size_t)t * CN4 + 4096 + h * CHVD + lane * 8;
    f32x4 ga = *(const f32x4*)(Cb + gb);
    f32x4 gbv = *(const f32x4*)(Cb + gb + 4);
    f32x4 wa = *(const f32x4*)(o_norm_w + lane * 8);
    f32x4 wbv = *(const f32x4*)(o_norm_w + lane * 8 + 4);

    us8 o8;
    #pragma unroll
    for (int r = 0; r < 4; r++) {
        o8[r]     = f2bf(va[r] * rinv * wa[r]  * sigmoidf(ga[r]));
        o8[4 + r] = f2bf(vb[r] * rinv * wbv[r] * sigmoidf(gbv[r]));
    }
    *(us8*)(actb + (size_t)t * CVD + h * CHVD + lane * 8) = o8;
}

// ---------------------------------------------------------------------------
// K7: output GEMM  d_out[T][2048] = act[T][2048] @ o_w^T   (fp32 out)
// 128x128 tile, BK=64, double-buffered 64 KB LDS, XOR swizzle both-sides,
// 1 barrier per K-tile, bijective XCD swizzle. Grid = 256 x 1 (1-D!).
// ---------------------------------------------------------------------------
__global__ __launch_bounds__(256) void gemm_o(
    const unsigned short* __restrict__ A,
    const unsigned short* __restrict__ W,
    float* __restrict__ Out)
{
    int id = blockIdx.x;
    int wg = (id & 7) * 32 + (id >> 3);   // XCD swizzle (256 % 8 == 0)
    int m0 = (wg & 15) * 128;
    int n0 = (wg >> 4) * 128;

    __shared__ __align__(16) unsigned short As[2][128 * 64];  // 2 x 16 KB
    __shared__ __align__(16) unsigned short Bs[2][128 * 64];  // 2 x 16 KB

    int tid = threadIdx.x;
    int wv = tid >> 6, lane = tid & 63;
    int wr = wv >> 1, wn = wv & 1;        // 2 x 2 wave grid, 64x64 per wave
    int lrow = lane & 15, quad = lane >> 4;

    f32x4 acc[4][4];
    #pragma unroll
    for (int i = 0; i < 4; i++)
        #pragma unroll
        for (int j = 0; j < 4; j++) { f32x4 z = {0.f,0.f,0.f,0.f}; acc[i][j] = z; }

    int wbase = (tid & ~63);

    #define STAGE_O(d, kt)                                                      \
    {                                                                           \
        int kb = (kt) * 64;                                                     \
        _Pragma("unroll")                                                       \
        for (int i = 0; i < 4; i++) {                                           \
            int c = i * 256 + tid;                                              \
            int r = c >> 3, cbk = (c & 7) ^ (r & 7);                            \
            async16(A + (size_t)(m0 + r) * CVD + kb + cbk * 8,                  \
                    &As[d][(i * 256 + wbase) * 8]);                             \
            async16(W + (size_t)(n0 + r) * CVD + kb + cbk * 8,                  \
                    &Bs[d][(i * 256 + wbase) * 8]);                             \
        }                                                                       \
    }

    STAGE_O(0, 0);
    __syncthreads();

    for (int kt = 0; kt < 32; kt++) {
        int cur = kt & 1;
        if (kt < 31) STAGE_O(cur ^ 1, kt + 1);

        #pragma unroll
        for (int ks = 0; ks < 2; ks++) {
            bf16x8 af[4], bfr[4];
            #pragma unroll
            for (int mf = 0; mf < 4; mf++) {
                int row = wr * 64 + mf * 16 + lrow;
                af[mf] = *(const bf16x8*)(&As[cur][row * 64 + (((ks * 4 + quad) ^ (row & 7)) * 8)]);
            }
            #pragma unroll
            for (int nf = 0; nf < 4; nf++) {
                int row = wn * 64 + nf * 16 + lrow;
                bfr[nf] = *(const bf16x8*)(&Bs[cur][row * 64 + (((ks * 4 + quad) ^ (row & 7)) * 8)]);
            }
            #pragma unroll
            for (int mf = 0; mf < 4; mf++)
                #pragma unroll
                for (int nf = 0; nf < 4; nf++)
                    acc[mf][nf] = __builtin_amdgcn_mfma_f32_16x16x32_bf16(af[mf], bfr[nf], acc[mf][nf], 0, 0, 0);
        }
        __syncthreads();
    }
    #undef STAGE_O

    #pragma unroll
    for (int mf = 0; mf < 4; mf++)
        #pragma unroll
        for (int nf = 0; nf < 4; nf++) {
            int gn = n0 + wn * 64 + nf * 16 + lrow;
            #pragma unroll
            for (int r = 0; r < 4; r++) {
                int gm = m0 + wr * 64 + mf * 16 + quad * 4 + r;
                Out[(size_t)gm * CHID + gn] = acc[mf][nf][r];
            }
        }
}

// ---------------------------------------------------------------------------
extern "C" void kernel_launch(void* const* d_in, const int* in_sizes, int n_in,
                              void* d_out, int out_size, void* d_ws, size_t ws_size,
                              hipStream_t stream)
{
    const float* x      = (const float*)d_in[0];
    const float* gate_w = (const float*)d_in[1];
    const float* q_w    = (const float*)d_in[2];
    const float* k_w    = (const float*)d_in[3];
    const float* v_w    = (const float*)d_in[4];
    const float* b_w    = (const float*)d_in[5];
    const float* a_w    = (const float*)d_in[6];
    const float* g_w    = (const float*)d_in[7];
    const float* o_w    = (const float*)d_in[8];
    const float* A_log  = (const float*)d_in[9];
    const float* dt_b   = (const float*)d_in[10];
    const float* onw    = (const float*)d_in[11];

    char* ws = (char*)d_ws;
    float*          Cb       = (float*)(ws + 0);                  // 50331648 B
    float*          oslot    = (float*)(ws + 50331648);           // 33554432 B
    unsigned short* actb     = (unsigned short*)(ws + 83886080);  //  8388608 B
    unsigned short* qkbf     = actb;                              // overlay: qkbf dies before actb born
    unsigned short* xb       = (unsigned short*)(ws + 92274688);  //  8388608 B
    unsigned short* wb       = (unsigned short*)(ws + 100663296); // 25165824 B
    unsigned short* owb      = (unsigned short*)(ws + 125829120); //  8388608 B
    int*            tok_sel  = (int*)(ws + 134217728);
    float*          tok_w    = (float*)(ws + 134234112);
    float*          tok_beta = (float*)(ws + 134250496);
    float*          tok_glog = (float*)(ws + 134283264);
    int*            cnt      = (int*)(ws + 134316032);
    int*            lists    = (int*)(ws + 134316160);
    float*          wlists   = (float*)(ws + 134381696);
    // chunk_pre outputs overlay the dead xb+wb window (dead after gemm_qkvg):
    unsigned short* Wvg      = (unsigned short*)(ws + 92274688);  // 640*32KB = 20971520 B
    unsigned short* Sgg      = (unsigned short*)(ws + 113246208); // 640*2KB  =  1310720 B
    unsigned short* M2g      = (unsigned short*)(ws + 114556928); // 640*2KB  =  1310720 B
    float*          ginfo    = (float*)(ws + 115867648);          // 640*256B =   163840 B
    int*            coff     = (int*)(ws + 116031488);            // 132 B

    cvt_all<<<dim3(20480), dim3(256), 0, stream>>>(x, q_w, k_w, v_w, g_w, o_w,
                                                   xb, wb, owb);
    prep_kernel<<<dim3(CT), dim3(256), 0, stream>>>(x, gate_w, b_w, a_w, A_log, dt_b,
                                                    tok_sel, tok_w, tok_beta, tok_glog);
    compact_kernel<<<dim3(CB * CNM), dim3(512), 0, stream>>>(tok_sel, tok_w, cnt, lists, wlists);
    gemm_qkvg<<<dim3(256), dim3(512), 0, stream>>>(xb, wb, Cb);
    chunk_off_kernel<<<dim3(1), dim3(64), 0, stream>>>(cnt, coff);
    act_qkv<<<dim3(CT), dim3(256), 0, stream>>>(Cb, qkbf);
    chunk_pre<<<dim3(32, 16, 4), dim3(256), 0, stream>>>(qkbf, Cb, tok_beta, tok_glog,
                                                         cnt, coff, lists,
                                                         Wvg, Sgg, M2g, ginfo);
    recur_kernel<<<dim3(512), dim3(512), 0, stream>>>(qkbf, cnt, coff, lists, wlists,
                                                      Wvg, Sgg, M2g, ginfo, oslot);
    act_gate<<<dim3(CT), dim3(256), 0, stream>>>(oslot, Cb, onw, actb);
    gemm_o<<<dim3(256), dim3(256), 0, stream>>>(actb, owb, (float*)d_out);
}